// Round 6
// baseline (260.802 us; speedup 1.0000x reference)
//
#include <hip/hip_runtime.h>
#include <hip/hip_bf16.h>

#define FEAT 128
#define RBITS 13
#define RSIZE 8192           // partition width (8 K nodes)
#define NCHUNK 64            // edge chunks

typedef __attribute__((ext_vector_type(8))) short short8;
typedef __attribute__((ext_vector_type(4))) short short4v;
typedef __attribute__((ext_vector_type(4))) float f32x4;

__device__ __forceinline__ ushort f2bf(float f) {
    union { float f; unsigned u; } v; v.f = f;
    unsigned u = v.u;
    unsigned r = 0x7fffu + ((u >> 16) & 1u);
    return (ushort)((u + r) >> 16);
}
__device__ __forceinline__ float bf2f(short s) {
    union { unsigned u; float f; } v;
    v.u = ((unsigned)(ushort)s) << 16;
    return v.f;
}

// ---------------------------------------------------------------- A: fused src+dst partial histograms, u8-packed LDS
// grid (NCHUNK, P). partial{Src,Dst}[p][c][r] as packed u8 (stored as u32 words).
__global__ __launch_bounds__(256)
void hist_kernel(const int* __restrict__ src, const int* __restrict__ dst,
                 unsigned* __restrict__ partialSrc, unsigned* __restrict__ partialDst,
                 int E, int CS)
{
    __shared__ unsigned hs[RSIZE / 4];
    __shared__ unsigned hd[RSIZE / 4];
    const int c = blockIdx.x, p = blockIdx.y;
    for (int r = threadIdx.x; r < RSIZE / 4; r += 256) { hs[r] = 0; hd[r] = 0; }
    __syncthreads();
    const int e0 = c * CS, e1 = min(E, e0 + CS);
    for (int e = e0 + threadIdx.x; e < e1; e += 256) {
        int s = src[e];
        if ((s >> RBITS) == p) {
            int r = s & (RSIZE - 1);
            atomicAdd(&hs[r >> 2], 1u << ((r & 3) * 8));
        }
        int d = dst[e];
        if ((d >> RBITS) == p) {
            int r = d & (RSIZE - 1);
            atomicAdd(&hd[r >> 2], 1u << ((r & 3) * 8));
        }
    }
    __syncthreads();
    const size_t base = ((size_t)p * NCHUNK + c) * (RSIZE / 4);
    for (int r = threadIdx.x; r < RSIZE / 4; r += 256) {
        partialSrc[base + r] = hs[r];
        partialDst[base + r] = hd[r];
    }
}

// ---------------------------------------------------------------- B: merge -> degrees/norms + u8 chunk offsets (+ fused scan1)
// partialDst (u8 view) is rewritten in place with per-chunk EXCLUSIVE offsets.
__global__ __launch_bounds__(256)
void merge_kernel(const unsigned char* __restrict__ ps8, unsigned char* __restrict__ pd8,
                  int* __restrict__ cntIn, float* __restrict__ normOut,
                  float* __restrict__ normIn, int* __restrict__ blockSums, int N)
{
    const int n = blockIdx.x * 256 + threadIdx.x;
    unsigned off = 0;
    if (n < N) {
        const int p = n >> RBITS, r = n & (RSIZE - 1);
        const size_t base = (size_t)p * NCHUNK * RSIZE + r;
        unsigned so = 0;
#pragma unroll 8
        for (int c = 0; c < NCHUNK; ++c) so += ps8[base + (size_t)c * RSIZE];
#pragma unroll 8
        for (int c = 0; c < NCHUNK; ++c) {
            size_t i = base + (size_t)c * RSIZE;
            unsigned t = pd8[i];
            pd8[i] = (unsigned char)off;
            off += t;
        }
        cntIn[n]   = (int)off;
        normIn[n]  = off ? rsqrtf((float)off) : 0.0f;
        normOut[n] = so  ? rsqrtf((float)so)  : 0.0f;
    }
    // fused scan1: per-block sum of cntIn
    __shared__ int sh[256];
    sh[threadIdx.x] = (int)off;
    __syncthreads();
    for (int o = 128; o > 0; o >>= 1) {
        if (threadIdx.x < o) sh[threadIdx.x] += sh[threadIdx.x + o];
        __syncthreads();
    }
    if (threadIdx.x == 0) blockSums[blockIdx.x] = sh[0];
}

// ---------------------------------------------------------------- rowStart (+ colsum zero)
__global__ __launch_bounds__(256)
void rowstart_kernel(const int* __restrict__ cntIn, const int* __restrict__ blockSums,
                     int* __restrict__ rowStart, float* __restrict__ colsum,
                     int N, int NB, int E)
{
    __shared__ int bs[256];
    __shared__ int bse[256];
    __shared__ int sh[256];
    const int t = threadIdx.x;
    int bv = (t < NB) ? blockSums[t] : 0;
    bs[t] = bv;
    __syncthreads();
    for (int off = 1; off < 256; off <<= 1) {
        int u = (t >= off) ? bs[t - off] : 0;
        __syncthreads();
        bs[t] += u;
        __syncthreads();
    }
    bse[t] = bs[t] - bv;
    __syncthreads();

    const int i = blockIdx.x * 256 + t;
    int v = (i < N) ? cntIn[i] : 0;
    sh[t] = v;
    __syncthreads();
    for (int off = 1; off < 256; off <<= 1) {
        int u = (t >= off) ? sh[t - off] : 0;
        __syncthreads();
        sh[t] += u;
        __syncthreads();
    }
    if (i < N) rowStart[i] = bse[blockIdx.x] + sh[t] - v;
    if (blockIdx.x == 0) {
        if (t == 0) rowStart[N] = E;
        colsum[t] = 0.0f;
    }
}

// ---------------------------------------------------------------- fill: LDS cursor counting sort, grid (NCHUNK, P)
__global__ __launch_bounds__(256)
void fill_kernel(const int* __restrict__ src, const int* __restrict__ dst,
                 const int* __restrict__ rowStart, const unsigned char* __restrict__ chunkOff8,
                 int* __restrict__ csrSrc, int N, int E, int CS)
{
    __shared__ unsigned cursor[RSIZE];    // 32 KB
    const int c = blockIdx.x, p = blockIdx.y;
    const unsigned char* co = chunkOff8 + ((size_t)p * NCHUNK + c) * RSIZE;
    for (int r = threadIdx.x; r < RSIZE; r += 256) {
        int n = (p << RBITS) + r;
        cursor[r] = (n < N) ? (unsigned)rowStart[n] + (unsigned)co[r] : 0u;
    }
    __syncthreads();
    const int e0 = c * CS, e1 = min(E, e0 + CS);
    for (int e = e0 + threadIdx.x; e < e1; e += 256) {
        int d = dst[e];
        if ((d >> RBITS) == p) {
            unsigned pos = atomicAdd(&cursor[d & (RSIZE - 1)], 1u);
            csrSrc[pos] = src[e];
        }
    }
}

// ---------------------------------------------------------------- MFMA GEMM (bf16), optional fp32 input, 1 strip/block
template<bool F32IN>
__global__ __launch_bounds__(256)
void gemm_mfma_kernel(const void* __restrict__ Ain, const float* __restrict__ W,
                      const float* __restrict__ scale, ushort* __restrict__ C, int M)
{
    __shared__ ushort WT[128 * 132];   // [col][k]
    __shared__ ushort As[64 * 132];    // [row][k]
    __shared__ float  sScale[64];

    const int tid  = threadIdx.x;
    const int wv   = tid >> 6;
    const int lane = tid & 63;
    const int rowHalf = wv >> 1;
    const int colHalf = wv & 1;
    const int l15  = lane & 15;
    const int quad = lane >> 4;
    const int row0 = blockIdx.x << 6;

    // stage WT = bf16(W)^T and A strip concurrently
    for (int it = 0; it < 16; ++it) {
        int fid = tid + (it << 8);
        int k   = fid >> 5;
        int c4  = (fid & 31) << 2;
        float4 w = *(const float4*)(W + (size_t)k * FEAT + c4);
        WT[(c4 + 0) * 132 + k] = f2bf(w.x);
        WT[(c4 + 1) * 132 + k] = f2bf(w.y);
        WT[(c4 + 2) * 132 + k] = f2bf(w.z);
        WT[(c4 + 3) * 132 + k] = f2bf(w.w);
    }
#pragma unroll
    for (int it = 0; it < 4; ++it) {
        int fid = tid + (it << 8);
        int r   = fid >> 4;
        int seg = (fid & 15) << 3;
        int grow = row0 + r;
        short4v lo = {0, 0, 0, 0}, hi = {0, 0, 0, 0};
        if (grow < M) {
            if (F32IN) {
                const float* pa = (const float*)Ain + (size_t)grow * FEAT + seg;
                float4 u0 = *(const float4*)(pa);
                float4 u1 = *(const float4*)(pa + 4);
                lo[0] = (short)f2bf(u0.x); lo[1] = (short)f2bf(u0.y);
                lo[2] = (short)f2bf(u0.z); lo[3] = (short)f2bf(u0.w);
                hi[0] = (short)f2bf(u1.x); hi[1] = (short)f2bf(u1.y);
                hi[2] = (short)f2bf(u1.z); hi[3] = (short)f2bf(u1.w);
            } else {
                const ushort* pa = (const ushort*)Ain + (size_t)grow * FEAT + seg;
                lo = *(const short4v*)(pa);
                hi = *(const short4v*)(pa + 4);
            }
        }
        *(short4v*)&As[r * 132 + seg]     = lo;
        *(short4v*)&As[r * 132 + seg + 4] = hi;
    }
    if (tid < 64) {
        int grow = row0 + tid;
        sScale[tid] = (grow < M) ? scale[grow] : 0.0f;
    }
    __syncthreads();

    f32x4 acc[2][4] = {};
#pragma unroll
    for (int kst = 0; kst < 4; ++kst) {
        int k = kst * 32 + quad * 8;
        short8 af[2];
#pragma unroll
        for (int rt = 0; rt < 2; ++rt) {
            int row = rowHalf * 32 + rt * 16 + l15;
            short4v lo = *(const short4v*)&As[row * 132 + k];
            short4v hi = *(const short4v*)&As[row * 132 + k + 4];
            af[rt] = __builtin_shufflevector(lo, hi, 0, 1, 2, 3, 4, 5, 6, 7);
        }
        short8 bf[4];
#pragma unroll
        for (int ct = 0; ct < 4; ++ct) {
            int col = colHalf * 64 + ct * 16 + l15;
            short4v lo = *(const short4v*)&WT[col * 132 + k];
            short4v hi = *(const short4v*)&WT[col * 132 + k + 4];
            bf[ct] = __builtin_shufflevector(lo, hi, 0, 1, 2, 3, 4, 5, 6, 7);
        }
#pragma unroll
        for (int rt = 0; rt < 2; ++rt)
#pragma unroll
            for (int ct = 0; ct < 4; ++ct)
                acc[rt][ct] = __builtin_amdgcn_mfma_f32_16x16x32_bf16(
                    af[rt], bf[ct], acc[rt][ct], 0, 0, 0);
    }

#pragma unroll
    for (int rt = 0; rt < 2; ++rt) {
        int rbase = rowHalf * 32 + rt * 16 + quad * 4;
#pragma unroll
        for (int reg = 0; reg < 4; ++reg) {
            int rl = rbase + reg;
            int grow = row0 + rl;
            if (grow < M) {
                float sc = sScale[rl];
#pragma unroll
                for (int ct = 0; ct < 4; ++ct) {
                    int col = colHalf * 64 + ct * 16 + l15;
                    C[(size_t)grow * FEAT + col] = f2bf(acc[rt][ct][reg] * sc);
                }
            }
        }
    }
}

// ---------------------------------------------------------------- gather + fused relu(agg*normIn + bias)
__global__ __launch_bounds__(256)
void gather_kernel(const ushort* __restrict__ t, const int* __restrict__ rowStart,
                   const int* __restrict__ csrSrc, const float* __restrict__ normIn,
                   const float* __restrict__ bias, ushort* __restrict__ out, int N)
{
    const int hw   = threadIdx.x >> 5;
    const int lane = threadIdx.x & 31;
    const int node = blockIdx.x * 8 + hw;
    if (node >= N) return;
    const int s = rowStart[node];
    const int e = rowStart[node + 1];
    float a0 = 0.f, a1 = 0.f, a2 = 0.f, a3 = 0.f;
    for (int base = s; base < e; base += 32) {
        const int m = min(32, e - base);
        int idx = (base + lane < e) ? csrSrc[base + lane] : 0;
        int j = 0;
        for (; j + 4 <= m; j += 4) {
            int s0 = __shfl(idx, j,     32);
            int s1 = __shfl(idx, j + 1, 32);
            int s2 = __shfl(idx, j + 2, 32);
            int s3 = __shfl(idx, j + 3, 32);
            short4v v0 = *(const short4v*)(t + (size_t)s0 * FEAT + lane * 4);
            short4v v1 = *(const short4v*)(t + (size_t)s1 * FEAT + lane * 4);
            short4v v2 = *(const short4v*)(t + (size_t)s2 * FEAT + lane * 4);
            short4v v3 = *(const short4v*)(t + (size_t)s3 * FEAT + lane * 4);
            a0 += bf2f(v0[0]) + bf2f(v1[0]) + bf2f(v2[0]) + bf2f(v3[0]);
            a1 += bf2f(v0[1]) + bf2f(v1[1]) + bf2f(v2[1]) + bf2f(v3[1]);
            a2 += bf2f(v0[2]) + bf2f(v1[2]) + bf2f(v2[2]) + bf2f(v3[2]);
            a3 += bf2f(v0[3]) + bf2f(v1[3]) + bf2f(v2[3]) + bf2f(v3[3]);
        }
        for (; j < m; ++j) {
            int srcn = __shfl(idx, j, 32);
            short4v v = *(const short4v*)(t + (size_t)srcn * FEAT + lane * 4);
            a0 += bf2f(v[0]); a1 += bf2f(v[1]); a2 += bf2f(v[2]); a3 += bf2f(v[3]);
        }
    }
    float ni = normIn[node];
    float4 b = *(const float4*)(bias + lane * 4);
    short4v o;
    o[0] = (short)f2bf(fmaxf(fmaf(a0, ni, b.x), 0.0f));
    o[1] = (short)f2bf(fmaxf(fmaf(a1, ni, b.y), 0.0f));
    o[2] = (short)f2bf(fmaxf(fmaf(a2, ni, b.z), 0.0f));
    o[3] = (short)f2bf(fmaxf(fmaf(a3, ni, b.w), 0.0f));
    *(short4v*)(out + (size_t)node * FEAT + lane * 4) = o;
}

// ---------------------------------------------------------------- column sum of bf16 h2
__global__ __launch_bounds__(256)
void colreduce_kernel(const ushort* __restrict__ h2, float* __restrict__ colsum, int N)
{
    const int c  = threadIdx.x & 127;
    const int rg = threadIdx.x >> 7;
    const int r0 = blockIdx.x * 256;
    const int rEnd = min(r0 + 256, N);
    float acc = 0.0f;
    for (int r = r0 + rg; r < rEnd; r += 2)
        acc += bf2f(h2[(size_t)r * FEAT + c]);
    __shared__ float sh[256];
    sh[threadIdx.x] = acc;
    __syncthreads();
    if (rg == 0) unsafeAtomicAdd(&colsum[c], sh[c] + sh[128 + c]);
}

// ---------------------------------------------------------------- final readout
__global__ __launch_bounds__(128)
void final_kernel(const float* __restrict__ colsum, const float* __restrict__ Wr,
                  const float* __restrict__ br, float* __restrict__ out, float invN)
{
    __shared__ float s0[128], s1[128];
    int j = threadIdx.x;
    float hg = colsum[j] * invN;
    s0[j] = hg * Wr[2 * j + 0];
    s1[j] = hg * Wr[2 * j + 1];
    __syncthreads();
    for (int off = 64; off > 0; off >>= 1) {
        if (j < off) { s0[j] += s0[j + off]; s1[j] += s1[j + off]; }
        __syncthreads();
    }
    if (j == 0) {
        out[0] = s0[0] + br[0];
        out[1] = s1[0] + br[1];
    }
}

// ---------------------------------------------------------------- launch
extern "C" void kernel_launch(void* const* d_in, const int* in_sizes, int n_in,
                              void* d_out, int out_size, void* d_ws, size_t ws_size,
                              hipStream_t stream)
{
    const float* x   = (const float*)d_in[0];
    const int*   src = (const int*)d_in[1];
    const int*   dst = (const int*)d_in[2];
    const float* W1  = (const float*)d_in[3];
    const float* b1  = (const float*)d_in[4];
    const float* W2  = (const float*)d_in[5];
    const float* b2  = (const float*)d_in[6];
    const float* Wr  = (const float*)d_in[7];
    const float* br  = (const float*)d_in[8];
    float* out = (float*)d_out;

    const int N = in_sizes[0] / FEAT;             // 50000
    const int E = in_sizes[1];                    // 640000
    const int NP = ((N + 255) / 256) * 256;
    const int NB = (N + 255) / 256;               // <= 256
    const int P  = (N + RSIZE - 1) / RSIZE;       // 7
    const int CS = (E + NCHUNK - 1) / NCHUNK;     // 10000

    // workspace layout
    char* p = (char*)d_ws;
    unsigned* partialSrc = (unsigned*)p;  p += (size_t)P * NCHUNK * (RSIZE / 4) * 4;
    unsigned* partialDst = (unsigned*)p;  p += (size_t)P * NCHUNK * (RSIZE / 4) * 4;
    float*  colsum    = (float*)p;        p += 256 * 4;
    int*    blockSums = (int*)p;          p += 256 * 4;
    int*    cntIn     = (int*)p;          p += (size_t)NP * 4;
    float*  normOut   = (float*)p;        p += (size_t)NP * 4;
    float*  normIn    = (float*)p;        p += (size_t)NP * 4;
    int*    rowStart  = (int*)p;          p += (size_t)(NP + 64) * 4;
    int*    csrSrc    = (int*)p;          p += (size_t)E * 4;
    ushort* bufT      = (ushort*)p;       p += (size_t)N * FEAT * 2;
    ushort* bufH      = (ushort*)p;       p += (size_t)N * FEAT * 2;

    // CSR + degree pipeline (no memory-side atomics, u8 partials)
    hist_kernel<<<dim3(NCHUNK, P), 256, 0, stream>>>(src, dst, partialSrc, partialDst, E, CS);
    merge_kernel<<<NB, 256, 0, stream>>>((const unsigned char*)partialSrc,
                                         (unsigned char*)partialDst,
                                         cntIn, normOut, normIn, blockSums, N);
    rowstart_kernel<<<NB, 256, 0, stream>>>(cntIn, blockSums, rowStart, colsum, N, NB, E);
    fill_kernel<<<dim3(NCHUNK, P), 256, 0, stream>>>(src, dst, rowStart,
                                                     (const unsigned char*)partialDst,
                                                     csrSrc, N, E, CS);

    const int nStrips = (N + 63) / 64;
    const int gathBlocks = (N + 7) / 8;

    // layer 1 (x fp32 consumed directly, converted inline)
    gemm_mfma_kernel<true><<<nStrips, 256, 0, stream>>>((const void*)x, W1, normOut, bufT, N);
    gather_kernel<<<gathBlocks, 256, 0, stream>>>(bufT, rowStart, csrSrc, normIn, b1, bufH, N);

    // layer 2
    gemm_mfma_kernel<false><<<nStrips, 256, 0, stream>>>((const void*)bufH, W2, normOut, bufT, N);
    gather_kernel<<<gathBlocks, 256, 0, stream>>>(bufT, rowStart, csrSrc, normIn, b2, bufH, N);

    // readout
    colreduce_kernel<<<NB, 256, 0, stream>>>(bufH, colsum, N);
    final_kernel<<<1, 128, 0, stream>>>(colsum, Wr, br, out, 1.0f / (float)N);
}